// Round 1
// baseline (217.529 us; speedup 1.0000x reference)
//
#include <hip/hip_runtime.h>

typedef unsigned short u16;
typedef __attribute__((ext_vector_type(8))) short short8;
typedef __attribute__((ext_vector_type(4))) float f32x4;

// ---------- helpers ----------
__device__ inline u16 f2bf(float f) {
    union { float f; unsigned u; } v; v.f = f;
    unsigned u = v.u;
    unsigned r = (u + 0x7FFFu + ((u >> 16) & 1u)) >> 16;
    return (u16)r;
}
__device__ inline float bf2f(u16 h) {
    union { unsigned u; float f; } v; v.u = ((unsigned)h) << 16;
    return v.f;
}
__device__ inline float ftanh(float x) {
    float e = __expf(2.f * x);
    return 1.f - 2.f / (e + 1.f);
}

// ---------- kernel 1: mask + bf16 cast + row squared-norms ----------
__global__ __launch_bounds__(128) void prep_kernel(
    const float* __restrict__ F0r, const float* __restrict__ F1r,
    const float* __restrict__ m0, const float* __restrict__ m1,
    u16* __restrict__ F0b, u16* __restrict__ F1b,
    float* __restrict__ sq0, float* __restrict__ sq1)
{
    int bs = blockIdx.x;          // b*256 + s
    int t = threadIdx.x;          // 128 threads, 4 floats each
    size_t base = (size_t)bs * 512 + t * 4;
    float mk0 = m0[bs], mk1 = m1[bs];
    float4 v0 = *(const float4*)(F0r + base);
    float4 v1 = *(const float4*)(F1r + base);
    v0.x *= mk0; v0.y *= mk0; v0.z *= mk0; v0.w *= mk0;
    v1.x *= mk1; v1.y *= mk1; v1.z *= mk1; v1.w *= mk1;
    ushort4 u0; u0.x = f2bf(v0.x); u0.y = f2bf(v0.y); u0.z = f2bf(v0.z); u0.w = f2bf(v0.w);
    ushort4 u1; u1.x = f2bf(v1.x); u1.y = f2bf(v1.y); u1.z = f2bf(v1.z); u1.w = f2bf(v1.w);
    *(ushort4*)(F0b + base) = u0;
    *(ushort4*)(F1b + base) = u1;
    float s0p = v0.x*v0.x + v0.y*v0.y + v0.z*v0.z + v0.w*v0.w;
    float s1p = v1.x*v1.x + v1.y*v1.y + v1.z*v1.z + v1.w*v1.w;
    #pragma unroll
    for (int off = 32; off > 0; off >>= 1) {
        s0p += __shfl_xor(s0p, off);
        s1p += __shfl_xor(s1p, off);
    }
    __shared__ float red0[2], red1[2];
    if ((t & 63) == 0) { red0[t >> 6] = s0p; red1[t >> 6] = s1p; }
    __syncthreads();
    if (t == 0) { sq0[bs] = red0[0] + red0[1]; sq1[bs] = red1[0] + red1[1]; }
}

// ---------- kernel 2: W [S,D] fp32 -> WT [D,S] bf16 ----------
__global__ __launch_bounds__(256) void wtrans_kernel(
    const float* __restrict__ W0, const float* __restrict__ W1,
    u16* __restrict__ WT0, u16* __restrict__ WT1)
{
    int idx = blockIdx.x * 256 + threadIdx.x;   // 0 .. 262143
    int a = idx >> 17;
    int r = idx & 131071;
    int s = r >> 9, d = r & 511;
    const float* W = a ? W1 : W0;
    u16* WT = a ? WT1 : WT0;
    WT[d * 256 + s] = f2bf(W[r]);
}

// ---------- shared GEMM core: 128x128 tile, K multiple of 64, bf16 MFMA ----------
// A: [M,K] row-major bf16 (lda), B: [N,K] row-major bf16 (ldb)  ->  C[m][n]
__device__ inline void gemm128_core(
    const u16* __restrict__ Ap, int lda,
    const u16* __restrict__ Bp, int ldb,
    int K, int m0, int n0,
    u16 (*As)[72], u16 (*Bs)[72],
    f32x4 acc[4][4])
{
    const int t = threadIdx.x;
    const int lane = t & 63, w = t >> 6;
    const int wm = w >> 1, wn = w & 1;
    const int q = lane >> 4, lm = lane & 15;

    for (int k0 = 0; k0 < K; k0 += 64) {
        #pragma unroll
        for (int i = 0; i < 4; ++i) {
            int idx = i * 256 + t;       // 0..1023
            int row = idx >> 3;          // 0..127
            int seg = idx & 7;           // 8 segs of 8 bf16 per row
            *(uint4*)&As[row][seg * 8] =
                *(const uint4*)(Ap + (size_t)(m0 + row) * lda + k0 + seg * 8);
            *(uint4*)&Bs[row][seg * 8] =
                *(const uint4*)(Bp + (size_t)(n0 + row) * ldb + k0 + seg * 8);
        }
        __syncthreads();
        #pragma unroll
        for (int ks = 0; ks < 64; ks += 32) {
            short8 af[4], bfr[4];
            #pragma unroll
            for (int x = 0; x < 4; ++x) {
                af[x]  = *(const short8*)&As[wm * 64 + x * 16 + lm][ks + q * 8];
                bfr[x] = *(const short8*)&Bs[wn * 64 + x * 16 + lm][ks + q * 8];
            }
            #pragma unroll
            for (int x = 0; x < 4; ++x)
                #pragma unroll
                for (int y = 0; y < 4; ++y)
                    acc[x][y] = __builtin_amdgcn_mfma_f32_16x16x32_bf16(
                        af[x], bfr[y], acc[x][y], 0, 0, 0);
        }
        __syncthreads();
    }
}

// ---------- kernel 3: cross-GEMM + A epilogue (var 0: A, var 1: A^T) ----------
__global__ __launch_bounds__(256) void gemm_cross_kernel(
    const u16* __restrict__ F0b, const u16* __restrict__ F1b,
    const float* __restrict__ sq0, const float* __restrict__ sq1,
    u16* __restrict__ Abf, u16* __restrict__ ATbf)
{
    __shared__ __align__(16) u16 As[128][72];
    __shared__ __align__(16) u16 Bs[128][72];
    int b = blockIdx.y, var = blockIdx.z;
    int m0 = (blockIdx.x >> 1) * 128, n0 = (blockIdx.x & 1) * 128;
    const u16 *Ap, *Bp; const float *sqR, *sqC; u16* Out;
    if (var == 0) {
        Ap = F0b + (size_t)b * 131072; Bp = F1b + (size_t)b * 131072;
        sqR = sq0 + b * 256; sqC = sq1 + b * 256;
        Out = Abf + (size_t)b * 65536;
    } else {
        Ap = F1b + (size_t)b * 131072; Bp = F0b + (size_t)b * 131072;
        sqR = sq1 + b * 256; sqC = sq0 + b * 256;
        Out = ATbf + (size_t)b * 65536;
    }
    f32x4 acc[4][4];
    #pragma unroll
    for (int x = 0; x < 4; ++x)
        #pragma unroll
        for (int y = 0; y < 4; ++y)
            acc[x][y] = (f32x4){0.f, 0.f, 0.f, 0.f};

    gemm128_core(Ap, 512, Bp, 512, 512, m0, n0, As, Bs, acc);

    const int t = threadIdx.x;
    const int lane = t & 63, w = t >> 6;
    const int wm = w >> 1, wn = w & 1, q = lane >> 4, lm = lane & 15;
    #pragma unroll
    for (int x = 0; x < 4; ++x) {
        #pragma unroll
        for (int r = 0; r < 4; ++r) {
            int i = m0 + wm * 64 + x * 16 + q * 4 + r;
            float si = sqR[i];
            #pragma unroll
            for (int y = 0; y < 4; ++y) {
                int j = n0 + wn * 64 + y * 16 + lm;
                float c = acc[x][y][r];
                float d2 = si + sqC[j] - 2.f * c;
                d2 = fmaxf(d2, 0.f);
                float a = 1.f / (1.f + sqrtf(d2));
                Out[(size_t)i * 256 + j] = f2bf(a);
            }
        }
    }
}

// ---------- kernel 4: Fa GEMMs (var 0: F0a = AT*WT0, var 1: F1a = A*WT1) ----------
__global__ __launch_bounds__(256) void gemm_fa_kernel(
    const u16* __restrict__ Abf, const u16* __restrict__ ATbf,
    const u16* __restrict__ WT0, const u16* __restrict__ WT1,
    u16* __restrict__ F0a, u16* __restrict__ F1a)
{
    __shared__ __align__(16) u16 As[128][72];
    __shared__ __align__(16) u16 Bs[128][72];
    int b = blockIdx.y, var = blockIdx.z;
    int m0 = (blockIdx.x >> 2) * 128;   // row tile (j or i), 0/128
    int n0 = (blockIdx.x & 3) * 128;    // d tile, 0..384
    const u16 *Ap, *Bp; u16* Out;
    if (var == 0) { Ap = ATbf + (size_t)b * 65536; Bp = WT0; Out = F0a + (size_t)b * 131072; }
    else          { Ap = Abf  + (size_t)b * 65536; Bp = WT1; Out = F1a + (size_t)b * 131072; }
    f32x4 acc[4][4];
    #pragma unroll
    for (int x = 0; x < 4; ++x)
        #pragma unroll
        for (int y = 0; y < 4; ++y)
            acc[x][y] = (f32x4){0.f, 0.f, 0.f, 0.f};

    gemm128_core(Ap, 256, Bp, 256, 256, m0, n0, As, Bs, acc);

    const int t = threadIdx.x;
    const int lane = t & 63, w = t >> 6;
    const int wm = w >> 1, wn = w & 1, q = lane >> 4, lm = lane & 15;
    #pragma unroll
    for (int x = 0; x < 4; ++x) {
        #pragma unroll
        for (int r = 0; r < 4; ++r) {
            int row = m0 + wm * 64 + x * 16 + q * 4 + r;
            #pragma unroll
            for (int y = 0; y < 4; ++y) {
                int col = n0 + wn * 64 + y * 16 + lm;
                Out[(size_t)row * 512 + col] = f2bf(acc[x][y][r]);
            }
        }
    }
}

// ---------- kernel 5: conv(2ch,3x1) + tanh + avgpool(3x1) ----------
__device__ inline void load_row_cv(
    const float* __restrict__ Fr, const float* __restrict__ mask,
    const u16* __restrict__ Fa, int s, int d0, float4& f, float4& a)
{
    if ((unsigned)s < 256u) {
        float4 v = *(const float4*)(Fr + (size_t)s * 512 + d0);
        float m = mask[s];
        f.x = v.x * m; f.y = v.y * m; f.z = v.z * m; f.w = v.w * m;
        ushort4 u = *(const ushort4*)(Fa + (size_t)s * 512 + d0);
        a.x = bf2f(u.x); a.y = bf2f(u.y); a.z = bf2f(u.z); a.w = bf2f(u.w);
    } else {
        f = make_float4(0.f, 0.f, 0.f, 0.f);
        a = make_float4(0.f, 0.f, 0.f, 0.f);
    }
}

__global__ __launch_bounds__(128) void conv_kernel(
    const float* __restrict__ F0r, const float* __restrict__ F1r,
    const float* __restrict__ m0, const float* __restrict__ m1,
    const u16* __restrict__ F0a, const u16* __restrict__ F1a,
    const float* __restrict__ cw, const float* __restrict__ cb,
    float* __restrict__ out)
{
    int b = blockIdx.y;
    int which = blockIdx.z;
    int s0 = blockIdx.x * 64;
    int d0 = threadIdx.x * 4;
    const float* Fr = (which ? F1r : F0r) + (size_t)b * 131072;
    const float* mask = (which ? m1 : m0) + b * 256;
    const u16* Fa = (which ? F1a : F0a) + (size_t)b * 131072;
    float* o = out + (size_t)which * 8388608 + (size_t)b * 131072 + d0;
    float w00 = cw[0], w01 = cw[1], w02 = cw[2];
    float w10 = cw[3], w11 = cw[4], w12 = cw[5];
    float bias = cb[0];

    float4 fm2, fm1, fc, fp1, fp2, am2, am1, ac, ap1, ap2;
    load_row_cv(Fr, mask, Fa, s0 - 2, d0, fm2, am2);
    load_row_cv(Fr, mask, Fa, s0 - 1, d0, fm1, am1);
    load_row_cv(Fr, mask, Fa, s0,     d0, fc,  ac);
    load_row_cv(Fr, mask, Fa, s0 + 1, d0, fp1, ap1);
    load_row_cv(Fr, mask, Fa, s0 + 2, d0, fp2, ap2);

    #define CONV_Y(Y, F0_, F1_, F2_, A0_, A1_, A2_)                                \
        { Y.x = bias + w00*F0_.x + w01*F1_.x + w02*F2_.x + w10*A0_.x + w11*A1_.x + w12*A2_.x; \
          Y.y = bias + w00*F0_.y + w01*F1_.y + w02*F2_.y + w10*A0_.y + w11*A1_.y + w12*A2_.y; \
          Y.z = bias + w00*F0_.z + w01*F1_.z + w02*F2_.z + w10*A0_.z + w11*A1_.z + w12*A2_.z; \
          Y.w = bias + w00*F0_.w + w01*F1_.w + w02*F2_.w + w10*A0_.w + w11*A1_.w + w12*A2_.w; }
    #define TANH4(Y) { Y.x = ftanh(Y.x); Y.y = ftanh(Y.y); Y.z = ftanh(Y.z); Y.w = ftanh(Y.w); }

    float4 ty0, ty1;
    CONV_Y(ty0, fm2, fm1, fc, am2, am1, ac); TANH4(ty0);
    CONV_Y(ty1, fm1, fc, fp1, am1, ac, ap1); TANH4(ty1);

    float4 w0f = fc, w1f = fp1, w2f = fp2;
    float4 w0a = ac, w1a = ap1, w2a = ap2;
    const float third = 1.f / 3.f;
    for (int s = s0; s < s0 + 64; ++s) {
        float4 ty2;
        CONV_Y(ty2, w0f, w1f, w2f, w0a, w1a, w2a); TANH4(ty2);
        float4 r;
        r.x = (ty0.x + ty1.x + ty2.x) * third;
        r.y = (ty0.y + ty1.y + ty2.y) * third;
        r.z = (ty0.z + ty1.z + ty2.z) * third;
        r.w = (ty0.w + ty1.w + ty2.w) * third;
        *(float4*)(o + (size_t)s * 512) = r;
        ty0 = ty1; ty1 = ty2;
        w0f = w1f; w1f = w2f;
        w0a = w1a; w1a = w2a;
        load_row_cv(Fr, mask, Fa, s + 3, d0, w2f, w2a);
    }
    #undef CONV_Y
    #undef TANH4
}

// ---------- launcher ----------
extern "C" void kernel_launch(void* const* d_in, const int* in_sizes, int n_in,
                              void* d_out, int out_size, void* d_ws, size_t ws_size,
                              hipStream_t stream)
{
    const float* F0r = (const float*)d_in[0];
    const float* F1r = (const float*)d_in[1];
    const float* m0  = (const float*)d_in[2];
    const float* m1  = (const float*)d_in[3];
    const float* W0  = (const float*)d_in[4];
    const float* W1  = (const float*)d_in[5];
    const float* cw  = (const float*)d_in[6];
    const float* cb  = (const float*)d_in[7];
    float* out = (float*)d_out;

    char* ws = (char*)d_ws;
    u16* F0b   = (u16*)(ws);                      // 16 MiB  [B,S,D] bf16
    u16* F1b   = (u16*)(ws + 16777216);           // 16 MiB
    u16* Abf   = (u16*)(ws + 33554432);           // 8 MiB   [B,S,S] bf16
    u16* ATbf  = (u16*)(ws + 41943040);           // 8 MiB
    float* sq0 = (float*)(ws + 50331648);         // 64 KiB
    float* sq1 = (float*)(ws + 50397184);         // 64 KiB
    u16* WT0   = (u16*)(ws + 50462720);           // 256 KiB [D,S] bf16
    u16* WT1   = (u16*)(ws + 50724864);           // 256 KiB
    // Fa aliases F bf16 buffers (F0b/F1b dead after gemm_cross_kernel)
    u16* F0a = F0b;
    u16* F1a = F1b;

    prep_kernel<<<16384, 128, 0, stream>>>(F0r, F1r, m0, m1, F0b, F1b, sq0, sq1);
    wtrans_kernel<<<1024, 256, 0, stream>>>(W0, W1, WT0, WT1);
    gemm_cross_kernel<<<dim3(4, 64, 2), 256, 0, stream>>>(F0b, F1b, sq0, sq1, Abf, ATbf);
    gemm_fa_kernel<<<dim3(8, 64, 2), 256, 0, stream>>>(Abf, ATbf, WT0, WT1, F0a, F1a);
    conv_kernel<<<dim3(4, 64, 2), 128, 0, stream>>>(F0r, F1r, m0, m1, F0a, F1a, cw, cb, out);
}

// Round 2
// 202.224 us; speedup vs baseline: 1.0757x; 1.0757x over previous
//
#include <hip/hip_runtime.h>

typedef unsigned short u16;
typedef __attribute__((ext_vector_type(8))) short short8;
typedef __attribute__((ext_vector_type(4))) float f32x4;

// ---------- helpers ----------
__device__ inline u16 f2bf(float f) {
    union { float f; unsigned u; } v; v.f = f;
    unsigned u = v.u;
    unsigned r = (u + 0x7FFFu + ((u >> 16) & 1u)) >> 16;
    return (u16)r;
}
__device__ inline float bf2f(u16 h) {
    union { unsigned u; float f; } v; v.u = ((unsigned)h) << 16;
    return v.f;
}
__device__ inline float ftanh(float x) {
    float e = __expf(2.f * x);
    return 1.f - 2.f / (e + 1.f);
}

// ---------- kernel 1: mask + bf16 cast + row squared-norms ----------
__global__ __launch_bounds__(128) void prep_kernel(
    const float* __restrict__ F0r, const float* __restrict__ F1r,
    const float* __restrict__ m0, const float* __restrict__ m1,
    u16* __restrict__ F0b, u16* __restrict__ F1b,
    float* __restrict__ sq0, float* __restrict__ sq1)
{
    int bs = blockIdx.x;          // b*256 + s
    int t = threadIdx.x;          // 128 threads, 4 floats each
    size_t base = (size_t)bs * 512 + t * 4;
    float mk0 = m0[bs], mk1 = m1[bs];
    float4 v0 = *(const float4*)(F0r + base);
    float4 v1 = *(const float4*)(F1r + base);
    v0.x *= mk0; v0.y *= mk0; v0.z *= mk0; v0.w *= mk0;
    v1.x *= mk1; v1.y *= mk1; v1.z *= mk1; v1.w *= mk1;
    ushort4 u0; u0.x = f2bf(v0.x); u0.y = f2bf(v0.y); u0.z = f2bf(v0.z); u0.w = f2bf(v0.w);
    ushort4 u1; u1.x = f2bf(v1.x); u1.y = f2bf(v1.y); u1.z = f2bf(v1.z); u1.w = f2bf(v1.w);
    *(ushort4*)(F0b + base) = u0;
    *(ushort4*)(F1b + base) = u1;
    float s0p = v0.x*v0.x + v0.y*v0.y + v0.z*v0.z + v0.w*v0.w;
    float s1p = v1.x*v1.x + v1.y*v1.y + v1.z*v1.z + v1.w*v1.w;
    #pragma unroll
    for (int off = 32; off > 0; off >>= 1) {
        s0p += __shfl_xor(s0p, off);
        s1p += __shfl_xor(s1p, off);
    }
    __shared__ float red0[2], red1[2];
    if ((t & 63) == 0) { red0[t >> 6] = s0p; red1[t >> 6] = s1p; }
    __syncthreads();
    if (t == 0) { sq0[bs] = red0[0] + red0[1]; sq1[bs] = red1[0] + red1[1]; }
}

// ---------- kernel 2: W [S,D] fp32 -> WT [D,S] bf16 ----------
__global__ __launch_bounds__(256) void wtrans_kernel(
    const float* __restrict__ W0, const float* __restrict__ W1,
    u16* __restrict__ WT0, u16* __restrict__ WT1)
{
    int idx = blockIdx.x * 256 + threadIdx.x;   // 0 .. 262143
    int a = idx >> 17;
    int r = idx & 131071;
    int s = r >> 9, d = r & 511;
    const float* W = a ? W1 : W0;
    u16* WT = a ? WT1 : WT0;
    WT[d * 256 + s] = f2bf(W[r]);
}

// ---------- shared GEMM core: 128x128 tile, K multiple of 64, bf16 MFMA ----------
// A: [M,K] row-major bf16 (lda), B: [N,K] row-major bf16 (ldb)  ->  C[m][n]
__device__ inline void gemm128_core(
    const u16* __restrict__ Ap, int lda,
    const u16* __restrict__ Bp, int ldb,
    int K, int m0, int n0,
    u16 (*As)[72], u16 (*Bs)[72],
    f32x4 acc[4][4])
{
    const int t = threadIdx.x;
    const int lane = t & 63, w = t >> 6;
    const int wm = w >> 1, wn = w & 1;
    const int q = lane >> 4, lm = lane & 15;

    for (int k0 = 0; k0 < K; k0 += 64) {
        #pragma unroll
        for (int i = 0; i < 4; ++i) {
            int idx = i * 256 + t;       // 0..1023
            int row = idx >> 3;          // 0..127
            int seg = idx & 7;           // 8 segs of 8 bf16 per row
            *(uint4*)&As[row][seg * 8] =
                *(const uint4*)(Ap + (size_t)(m0 + row) * lda + k0 + seg * 8);
            *(uint4*)&Bs[row][seg * 8] =
                *(const uint4*)(Bp + (size_t)(n0 + row) * ldb + k0 + seg * 8);
        }
        __syncthreads();
        #pragma unroll
        for (int ks = 0; ks < 64; ks += 32) {
            short8 af[4], bfr[4];
            #pragma unroll
            for (int x = 0; x < 4; ++x) {
                af[x]  = *(const short8*)&As[wm * 64 + x * 16 + lm][ks + q * 8];
                bfr[x] = *(const short8*)&Bs[wn * 64 + x * 16 + lm][ks + q * 8];
            }
            #pragma unroll
            for (int x = 0; x < 4; ++x)
                #pragma unroll
                for (int y = 0; y < 4; ++y)
                    acc[x][y] = __builtin_amdgcn_mfma_f32_16x16x32_bf16(
                        af[x], bfr[y], acc[x][y], 0, 0, 0);
        }
        __syncthreads();
    }
}

// ---------- kernel 3: cross-GEMM + A epilogue (var 0: A, var 1: A^T) ----------
__global__ __launch_bounds__(256) void gemm_cross_kernel(
    const u16* __restrict__ F0b, const u16* __restrict__ F1b,
    const float* __restrict__ sq0, const float* __restrict__ sq1,
    u16* __restrict__ Abf, u16* __restrict__ ATbf)
{
    __shared__ __align__(16) u16 As[128][72];
    __shared__ __align__(16) u16 Bs[128][72];
    int b = blockIdx.y, var = blockIdx.z;
    int m0 = (blockIdx.x >> 1) * 128, n0 = (blockIdx.x & 1) * 128;
    const u16 *Ap, *Bp; const float *sqR, *sqC; u16* Out;
    if (var == 0) {
        Ap = F0b + (size_t)b * 131072; Bp = F1b + (size_t)b * 131072;
        sqR = sq0 + b * 256; sqC = sq1 + b * 256;
        Out = Abf + (size_t)b * 65536;
    } else {
        Ap = F1b + (size_t)b * 131072; Bp = F0b + (size_t)b * 131072;
        sqR = sq1 + b * 256; sqC = sq0 + b * 256;
        Out = ATbf + (size_t)b * 65536;
    }
    f32x4 acc[4][4];
    #pragma unroll
    for (int x = 0; x < 4; ++x)
        #pragma unroll
        for (int y = 0; y < 4; ++y)
            acc[x][y] = (f32x4){0.f, 0.f, 0.f, 0.f};

    gemm128_core(Ap, 512, Bp, 512, 512, m0, n0, As, Bs, acc);

    const int t = threadIdx.x;
    const int lane = t & 63, w = t >> 6;
    const int wm = w >> 1, wn = w & 1, q = lane >> 4, lm = lane & 15;
    #pragma unroll
    for (int x = 0; x < 4; ++x) {
        #pragma unroll
        for (int r = 0; r < 4; ++r) {
            int i = m0 + wm * 64 + x * 16 + q * 4 + r;
            float si = sqR[i];
            #pragma unroll
            for (int y = 0; y < 4; ++y) {
                int j = n0 + wn * 64 + y * 16 + lm;
                float c = acc[x][y][r];
                float d2 = si + sqC[j] - 2.f * c;
                d2 = fmaxf(d2, 0.f);
                float a = 1.f / (1.f + sqrtf(d2));
                Out[(size_t)i * 256 + j] = f2bf(a);
            }
        }
    }
}

// ---------- kernel 4: Fa GEMMs (var 0: F0a = AT*WT0, var 1: F1a = A*WT1) ----------
__global__ __launch_bounds__(256) void gemm_fa_kernel(
    const u16* __restrict__ Abf, const u16* __restrict__ ATbf,
    const u16* __restrict__ WT0, const u16* __restrict__ WT1,
    u16* __restrict__ F0a, u16* __restrict__ F1a)
{
    __shared__ __align__(16) u16 As[128][72];
    __shared__ __align__(16) u16 Bs[128][72];
    int b = blockIdx.y, var = blockIdx.z;
    int m0 = (blockIdx.x >> 2) * 128;   // row tile (j or i), 0/128
    int n0 = (blockIdx.x & 3) * 128;    // d tile, 0..384
    const u16 *Ap, *Bp; u16* Out;
    if (var == 0) { Ap = ATbf + (size_t)b * 65536; Bp = WT0; Out = F0a + (size_t)b * 131072; }
    else          { Ap = Abf  + (size_t)b * 65536; Bp = WT1; Out = F1a + (size_t)b * 131072; }
    f32x4 acc[4][4];
    #pragma unroll
    for (int x = 0; x < 4; ++x)
        #pragma unroll
        for (int y = 0; y < 4; ++y)
            acc[x][y] = (f32x4){0.f, 0.f, 0.f, 0.f};

    gemm128_core(Ap, 256, Bp, 256, 256, m0, n0, As, Bs, acc);

    const int t = threadIdx.x;
    const int lane = t & 63, w = t >> 6;
    const int wm = w >> 1, wn = w & 1, q = lane >> 4, lm = lane & 15;
    #pragma unroll
    for (int x = 0; x < 4; ++x) {
        #pragma unroll
        for (int r = 0; r < 4; ++r) {
            int row = m0 + wm * 64 + x * 16 + q * 4 + r;
            #pragma unroll
            for (int y = 0; y < 4; ++y) {
                int col = n0 + wn * 64 + y * 16 + lm;
                Out[(size_t)row * 512 + col] = f2bf(acc[x][y][r]);
            }
        }
    }
}

// ---------- kernel 5: conv(2ch,3x1) + tanh + avgpool(3x1) ----------
__device__ inline void load_row_cv(
    const float* __restrict__ Fr, const float* __restrict__ mask,
    const u16* __restrict__ Fa, int s, int d0, float4& f, float4& a)
{
    if ((unsigned)s < 256u) {
        float4 v = *(const float4*)(Fr + (size_t)s * 512 + d0);
        float m = mask[s];
        f.x = v.x * m; f.y = v.y * m; f.z = v.z * m; f.w = v.w * m;
        ushort4 u = *(const ushort4*)(Fa + (size_t)s * 512 + d0);
        a.x = bf2f(u.x); a.y = bf2f(u.y); a.z = bf2f(u.z); a.w = bf2f(u.w);
    } else {
        f = make_float4(0.f, 0.f, 0.f, 0.f);
        a = make_float4(0.f, 0.f, 0.f, 0.f);
    }
}

// 16 s-rows per block (occupancy: grid 16*64*2=2048 blocks -> full wave supply)
__global__ __launch_bounds__(128) void conv_kernel(
    const float* __restrict__ F0r, const float* __restrict__ F1r,
    const float* __restrict__ m0, const float* __restrict__ m1,
    const u16* __restrict__ F0a, const u16* __restrict__ F1a,
    const float* __restrict__ cw, const float* __restrict__ cb,
    float* __restrict__ out)
{
    int b = blockIdx.y;
    int which = blockIdx.z;
    int s0 = blockIdx.x * 16;
    int d0 = threadIdx.x * 4;
    const float* Fr = (which ? F1r : F0r) + (size_t)b * 131072;
    const float* mask = (which ? m1 : m0) + b * 256;
    const u16* Fa = (which ? F1a : F0a) + (size_t)b * 131072;
    float* o = out + (size_t)which * 8388608 + (size_t)b * 131072 + d0;
    float w00 = cw[0], w01 = cw[1], w02 = cw[2];
    float w10 = cw[3], w11 = cw[4], w12 = cw[5];
    float bias = cb[0];

    float4 fm2, fm1, fc, fp1, fp2, am2, am1, ac, ap1, ap2;
    load_row_cv(Fr, mask, Fa, s0 - 2, d0, fm2, am2);
    load_row_cv(Fr, mask, Fa, s0 - 1, d0, fm1, am1);
    load_row_cv(Fr, mask, Fa, s0,     d0, fc,  ac);
    load_row_cv(Fr, mask, Fa, s0 + 1, d0, fp1, ap1);
    load_row_cv(Fr, mask, Fa, s0 + 2, d0, fp2, ap2);

    #define CONV_Y(Y, F0_, F1_, F2_, A0_, A1_, A2_)                                \
        { Y.x = bias + w00*F0_.x + w01*F1_.x + w02*F2_.x + w10*A0_.x + w11*A1_.x + w12*A2_.x; \
          Y.y = bias + w00*F0_.y + w01*F1_.y + w02*F2_.y + w10*A0_.y + w11*A1_.y + w12*A2_.y; \
          Y.z = bias + w00*F0_.z + w01*F1_.z + w02*F2_.z + w10*A0_.z + w11*A1_.z + w12*A2_.z; \
          Y.w = bias + w00*F0_.w + w01*F1_.w + w02*F2_.w + w10*A0_.w + w11*A1_.w + w12*A2_.w; }
    #define TANH4(Y) { Y.x = ftanh(Y.x); Y.y = ftanh(Y.y); Y.z = ftanh(Y.z); Y.w = ftanh(Y.w); }

    float4 ty0, ty1;
    CONV_Y(ty0, fm2, fm1, fc, am2, am1, ac); TANH4(ty0);
    CONV_Y(ty1, fm1, fc, fp1, am1, ac, ap1); TANH4(ty1);

    float4 w0f = fc, w1f = fp1, w2f = fp2;
    float4 w0a = ac, w1a = ap1, w2a = ap2;
    const float third = 1.f / 3.f;
    for (int s = s0; s < s0 + 16; ++s) {
        float4 ty2;
        CONV_Y(ty2, w0f, w1f, w2f, w0a, w1a, w2a); TANH4(ty2);
        float4 r;
        r.x = (ty0.x + ty1.x + ty2.x) * third;
        r.y = (ty0.y + ty1.y + ty2.y) * third;
        r.z = (ty0.z + ty1.z + ty2.z) * third;
        r.w = (ty0.w + ty1.w + ty2.w) * third;
        *(float4*)(o + (size_t)s * 512) = r;
        ty0 = ty1; ty1 = ty2;
        w0f = w1f; w1f = w2f;
        w0a = w1a; w1a = w2a;
        load_row_cv(Fr, mask, Fa, s + 3, d0, w2f, w2a);
    }
    #undef CONV_Y
    #undef TANH4
}

// ---------- launcher ----------
extern "C" void kernel_launch(void* const* d_in, const int* in_sizes, int n_in,
                              void* d_out, int out_size, void* d_ws, size_t ws_size,
                              hipStream_t stream)
{
    const float* F0r = (const float*)d_in[0];
    const float* F1r = (const float*)d_in[1];
    const float* m0  = (const float*)d_in[2];
    const float* m1  = (const float*)d_in[3];
    const float* W0  = (const float*)d_in[4];
    const float* W1  = (const float*)d_in[5];
    const float* cw  = (const float*)d_in[6];
    const float* cb  = (const float*)d_in[7];
    float* out = (float*)d_out;

    char* ws = (char*)d_ws;
    u16* F0b   = (u16*)(ws);                      // 16 MiB  [B,S,D] bf16
    u16* F1b   = (u16*)(ws + 16777216);           // 16 MiB
    u16* Abf   = (u16*)(ws + 33554432);           // 8 MiB   [B,S,S] bf16
    u16* ATbf  = (u16*)(ws + 41943040);           // 8 MiB
    float* sq0 = (float*)(ws + 50331648);         // 64 KiB
    float* sq1 = (float*)(ws + 50397184);         // 64 KiB
    u16* WT0   = (u16*)(ws + 50462720);           // 256 KiB [D,S] bf16
    u16* WT1   = (u16*)(ws + 50724864);           // 256 KiB
    // Fa aliases F bf16 buffers (F0b/F1b dead after gemm_cross_kernel)
    u16* F0a = F0b;
    u16* F1a = F1b;

    prep_kernel<<<16384, 128, 0, stream>>>(F0r, F1r, m0, m1, F0b, F1b, sq0, sq1);
    wtrans_kernel<<<1024, 256, 0, stream>>>(W0, W1, WT0, WT1);
    gemm_cross_kernel<<<dim3(4, 64, 2), 256, 0, stream>>>(F0b, F1b, sq0, sq1, Abf, ATbf);
    gemm_fa_kernel<<<dim3(8, 64, 2), 256, 0, stream>>>(Abf, ATbf, WT0, WT1, F0a, F1a);
    conv_kernel<<<dim3(16, 64, 2), 128, 0, stream>>>(F0r, F1r, m0, m1, F0a, F1a, cw, cb, out);
}